// Round 11
// baseline (74.228 us; speedup 1.0000x reference)
//
#include <hip/hip_runtime.h>
#include <cstdint>

// LIERE position encoder: batched expm of 8x8 skew-symmetric matrices.
// Cayley-Hamilton interpolation (as R10), rewritten on float2 ext-vectors so
// the backend can emit v_pk_fma_f32 (2 FMA/lane/instr). Scalar FP32 tops out
// at ~66% of the 157 TF peak (m07); packed math is the only way past it.
constexpr int LG   = 512;
constexpr int NPOS = 1025;
constexpr int NMAT = NPOS * LG;
constexpr int GEN_ELEMS = 2 * LG * 64;   // 256 KB

typedef float v2 __attribute__((ext_vector_type(2)));

__device__ __forceinline__ v2 sp(float s) { v2 r; r.x = s; r.y = s; return r; }
__device__ __forceinline__ v2 fma2(v2 a, v2 b, v2 c) {
#if __has_builtin(__builtin_elementwise_fma)
    return __builtin_elementwise_fma(a, b, c);
#else
    v2 r; r.x = fmaf(a.x, b.x, c.x); r.y = fmaf(a.y, b.y, c.y); return r;
#endif
}
__device__ __forceinline__ v2 abs2(v2 a) {
#if __has_builtin(__builtin_elementwise_abs)
    return __builtin_elementwise_abs(a);
#else
    v2 r; r.x = fabsf(a.x); r.y = fabsf(a.y); return r;
#endif
}

__host__ __device__ constexpr int UI(int i, int j) { return i*7 - (i*(i-1))/2 + (j - i - 1); }

// scalar element (i,k) of a packed [8][4] matrix (indices compile-time)
#define EL(M,i,k) (M[i][(k)>>1][(k)&1])

// D = A * B, all packed [8][4]
__device__ __forceinline__ void mmp(v2 (&D)[8][4], const v2 (&A)[8][4],
                                    const v2 (&B)[8][4]) {
    #pragma unroll
    for (int i = 0; i < 8; ++i)
        #pragma unroll
        for (int jp = 0; jp < 4; ++jp) {
            v2 acc = sp(EL(A,i,0)) * B[0][jp];
            #pragma unroll
            for (int k = 1; k < 8; ++k)
                acc = fma2(sp(EL(A,i,k)), B[k][jp], acc);
            D[i][jp] = acc;
        }
}

// transpose gen [2][512][64] -> genT [64][512][2]
__global__ __launch_bounds__(256)
void liere_tr_kernel(const float* __restrict__ g, float* __restrict__ gT) {
    int t = blockIdx.x * 256 + threadIdx.x;
    if (t >= GEN_ELEMS) return;
    int d  = t >> 15;
    int lg = (t >> 6) & 511;
    int e  = t & 63;
    gT[(size_t)e * 1024 + lg * 2 + d] = g[t];
}

template<bool TR>
__global__ __launch_bounds__(256)
void liere_expm_kernel(const float* __restrict__ pos,
                       const float* __restrict__ gen,
                       const float* __restrict__ genT,
                       float* __restrict__ out)
{
    const int bid = blockIdx.x, tid = threadIdx.x;
    const int n   = bid >> 1;                    // token, block-uniform
    const int lg  = ((bid & 1) << 8) | tid;

    v2 P[8][4];   // result, packed rows

    if (n == 0) {   // cls -> identity
        #pragma unroll
        for (int i = 0; i < 8; ++i)
            #pragma unroll
            for (int jp = 0; jp < 4; ++jp) {
                P[i][jp].x = (2*jp   == i) ? 1.f : 0.f;
                P[i][jp].y = (2*jp+1 == i) ? 1.f : 0.f;
            }
    } else {
        const float p0 = pos[(n-1)*2 + 0];
        const float p1 = pos[(n-1)*2 + 1];

        // ---- strict-upper scalars U of X = p0*B0 + p1*B1 ----
        float U[28];
        if (TR) {
            #pragma unroll
            for (int i = 0; i < 8; ++i)
                #pragma unroll
                for (int j = i+1; j < 8; ++j) {
                    const int e = i*8 + j;
                    float2 v = *reinterpret_cast<const float2*>(
                                   genT + (size_t)e * 1024 + lg * 2);
                    U[UI(i,j)] = fmaf(p0, v.x, p1 * v.y);
                }
        } else {
            const float* g0 = gen + (size_t)lg * 64;
            const float* g1 = g0 + (size_t)LG * 64;
            #pragma unroll
            for (int i = 0; i < 8; ++i)
                #pragma unroll
                for (int j = i+1; j < 8; ++j) {
                    const int e = i*8 + j;
                    U[UI(i,j)] = fmaf(p0, g0[e], p1 * g1[e]);
                }
        }

        // ---- Y = X^2 (packed; X materialized only for this step) ----
        v2 Y[8][4];
        {
            v2 X[8][4];
            #pragma unroll
            for (int i = 0; i < 8; ++i)
                #pragma unroll
                for (int jp = 0; jp < 4; ++jp) {
                    const int j0 = 2*jp, j1 = 2*jp+1;
                    X[i][jp].x = (i < j0) ? U[UI(i,j0)] : (i > j0) ? -U[UI(j0,i)] : 0.f;
                    X[i][jp].y = (i < j1) ? U[UI(i,j1)] : (i > j1) ? -U[UI(j1,i)] : 0.f;
                }
            mmp(Y, X, X);
        }   // X dead

        // ---- Y2 = Y^2 (packed) ----
        v2 Y2[8][4];
        mmp(Y2, Y, Y);

        // ---- traces: tr(Y); <Y,Y>=trY2; <Y,Y2>=trY3; <Y2,Y2>=trY4 ----
        float trY = 0.f;
        #pragma unroll
        for (int i = 0; i < 8; ++i) trY += EL(Y,i,i);
        v2 a2 = sp(0.f), a3 = sp(0.f), a4 = sp(0.f);
        #pragma unroll
        for (int i = 0; i < 8; ++i)
            #pragma unroll
            for (int jp = 0; jp < 4; ++jp) {
                a2 = fma2(Y[i][jp],  Y[i][jp],  a2);
                a3 = fma2(Y[i][jp],  Y2[i][jp], a3);
                a4 = fma2(Y2[i][jp], Y2[i][jp], a4);
            }
        const float sYY = a2.x + a2.y;   // tr(Y^2)
        const float sY3 = a3.x + a3.y;   // tr(Y^3) (negative)
        const float s44 = a4.x + a4.y;   // tr(Y^4)

        // ---- theta^4 <= min(||Y2||_inf, tr(Y^4)/2); wave-uniform r ----
        float yb = 0.f;
        #pragma unroll
        for (int i = 0; i < 8; ++i) {
            v2 s = abs2(Y2[i][0]) + abs2(Y2[i][1]) + abs2(Y2[i][2]) + abs2(Y2[i][3]);
            yb = fmaxf(yb, s.x + s.y);
        }
        float q4 = fmaxf(fminf(yb, 0.5f * s44), 1e-30f);
        #pragma unroll
        for (int off = 32; off >= 1; off >>= 1)
            q4 = fmaxf(q4, __shfl_xor(q4, off, 64));
        int r = (int)ceilf(0.25f * __log2f(q4) - 3.0f);   // theta/2^r <= 8
        if (r < 0) r = 0;
        if (r > 5) r = 5;

        // ---- Newton: p_m = (-1)^m tr(Y^m)/2 of {theta_k^2}, scaled ----
        const double R2 = (double)__uint_as_float((uint32_t)(127 - 2*r) << 23);
        const double R4 = R2 * R2;
        const double P1 = -0.5 * (double)trY * R2;
        const double P2 =  0.5 * (double)sYY * R4;
        const double P3 = -0.5 * (double)sY3 * R4 * R2;   // odd m: negate trace
        const double P4 =  0.5 * (double)s44 * R4 * R4;
        const double E1 = P1;
        const double E2 = 0.5 * (E1*P1 - P2);
        const double E3 = (1.0/3.0) * (E2*P1 - E1*P2 + P3);
        const double E4 = 0.25 * (E3*P1 - E2*P2 + E1*P3 - P4);

        float cf[8];
        {   // even cascade: 1/(2m)! reduced mod quartic in mu
            double c[16] = {
                1.0, 0.5, 0.041666666666666664, 0.001388888888888889,
                2.48015873015873e-5, 2.755731922398589e-7, 2.08767569878681e-9,
                1.1470745597729725e-11, 4.779477332387385e-14,
                1.5619206968586225e-16, 4.110317623312165e-19,
                8.896791392450574e-22, 1.6117375710961184e-24,
                2.4795962632247976e-27, 3.279889237069838e-30,
                3.7699876288159054e-33
            };
            #pragma unroll
            for (int m = 15; m >= 4; --m) {
                double t = c[m];
                c[m-1] = fma(-E1, t, c[m-1]);
                c[m-2] = fma(-E2, t, c[m-2]);
                c[m-3] = fma(-E3, t, c[m-3]);
                c[m-4] = fma(-E4, t, c[m-4]);
            }
            cf[0] = (float)c[0];
            cf[2] = (float)(c[1] * R2);
            cf[4] = (float)(c[2] * R4);
            cf[6] = (float)(c[3] * R4 * R2);
        }
        {   // odd cascade: 1/(2m+1)!
            double c[15] = {
                1.0, 0.16666666666666666, 0.008333333333333333,
                1.984126984126984e-4, 2.7557319223985893e-6,
                2.505210838544172e-8, 1.6059043836821613e-10,
                7.647163731819816e-13, 2.8114572543455206e-15,
                8.22063524662433e-18, 1.9572941063391263e-20,
                3.868170170630684e-23, 6.446950284384474e-26,
                9.183689863795546e-29, 1.1309962886447716e-31
            };
            #pragma unroll
            for (int m = 14; m >= 4; --m) {
                double t = c[m];
                c[m-1] = fma(-E1, t, c[m-1]);
                c[m-2] = fma(-E2, t, c[m-2]);
                c[m-3] = fma(-E3, t, c[m-3]);
                c[m-4] = fma(-E4, t, c[m-4]);
            }
            const double W1 = (double)__uint_as_float((uint32_t)(127 - r) << 23);
            cf[1] = (float)(c[0] * W1);
            cf[3] = (float)(c[1] * W1 * R2);
            cf[5] = (float)(c[2] * W1 * R4);
            cf[7] = (float)(c[3] * W1 * R4 * R2);
        }

        // ---- loop 1: per row k: Z_k = Y_k*Y2; E_k -> overwrite Y_k; O_k ----
        v2 O[8][4];
        #pragma unroll
        for (int k = 0; k < 8; ++k) {
            v2 Zr[4];
            #pragma unroll
            for (int jp = 0; jp < 4; ++jp) {
                v2 acc = sp(EL(Y,k,0)) * Y2[0][jp];
                #pragma unroll
                for (int m = 1; m < 8; ++m)
                    acc = fma2(sp(EL(Y,k,m)), Y2[m][jp], acc);
                Zr[jp] = acc;
            }
            #pragma unroll
            for (int jp = 0; jp < 4; ++jp) {
                v2 y = Y[k][jp], y2 = Y2[k][jp], z = Zr[jp];
                O[k][jp] = fma2(sp(cf[7]), z, fma2(sp(cf[5]), y2, sp(cf[3]) * y));
                Y[k][jp] = fma2(sp(cf[6]), z, fma2(sp(cf[4]), y2, sp(cf[2]) * y));
            }
            EL(Y,k,k) += cf[0];   // E diag
            EL(O,k,k) += cf[1];   // O diag
        }   // Y now holds E; Y2 dead

        // ---- loop 2: P_i = E_i + sum_k X_ik * O_k (X from U, skip k==i) ----
        #pragma unroll
        for (int i = 0; i < 8; ++i)
            #pragma unroll
            for (int jp = 0; jp < 4; ++jp) {
                v2 acc = Y[i][jp];   // E_i
                #pragma unroll
                for (int k = 0; k < 8; ++k) {
                    if (k == i) continue;
                    const float xik = (i < k) ? U[UI(i,k)] : -U[UI(k,i)];
                    acc = fma2(sp(xik), O[k][jp], acc);
                }
                P[i][jp] = acc;
            }

        // ---- r squarings, ping-pong (r wave-uniform -> scalar loop) ----
        {
            v2 Q[8][4];
            int pairs = r >> 1;
            while (pairs--) { mmp(Q, P, P); mmp(P, Q, Q); }
            if (r & 1) {
                mmp(Q, P, P);
                #pragma unroll
                for (int i = 0; i < 8; ++i)
                    #pragma unroll
                    for (int jp = 0; jp < 4; ++jp) P[i][jp] = Q[i][jp];
            }
        }
    }

    // ---- LDS-staged coalesced stores: 2 rounds of 32 floats/thread ----
    __shared__ float4 ls[256 * 8];   // 32 KB
    float4* o4base = reinterpret_cast<float4*>(out) + (size_t)bid * 4096;
    #pragma unroll
    for (int rr = 0; rr < 2; ++rr) {
        if (rr) __syncthreads();
        #pragma unroll
        for (int j = 0; j < 8; ++j) {
            const int jj = rr*8 + j;        // float4 index 0..15
            const int i = jj >> 1, h = jj & 1;
            ls[tid*8 + ((j + tid) & 7)] =
                make_float4(P[i][2*h].x, P[i][2*h].y, P[i][2*h+1].x, P[i][2*h+1].y);
        }
        __syncthreads();
        #pragma unroll
        for (int k = 0; k < 8; ++k) {
            const int u = k*256 + tid;
            const int o = u >> 3, cidx = u & 7;
            o4base[o*16 + cidx + 8*rr] = ls[o*8 + ((cidx + o) & 7)];
        }
    }
}

extern "C" void kernel_launch(void* const* d_in, const int* in_sizes, int n_in,
                              void* d_out, int out_size, void* d_ws, size_t ws_size,
                              hipStream_t stream) {
    const float* pos = (const float*)d_in[0];
    const float* gen = (const float*)d_in[1];
    float* out = (float*)d_out;

    const int block = 256;
    const int grid  = NMAT / block;             // 2050

    if (ws_size >= (size_t)GEN_ELEMS * sizeof(float)) {
        float* genT = (float*)d_ws;
        liere_tr_kernel<<<GEN_ELEMS / 256, 256, 0, stream>>>(gen, genT);
        liere_expm_kernel<true><<<grid, block, 0, stream>>>(pos, gen, genT, out);
    } else {
        liere_expm_kernel<false><<<grid, block, 0, stream>>>(pos, gen, nullptr, out);
    }
}

// Round 12
// 49.525 us; speedup vs baseline: 1.4988x; 1.4988x over previous
//
#include <hip/hip_runtime.h>
#include <cstdint>

// LIERE position encoder: batched expm of 8x8 skew-symmetric matrices.
// Cayley-Hamilton: exp(Xs) = deg-7 poly in Xs. Quartic q(mu)=prod(mu-theta_k^2)
// from Newton identities (p_m = (-1)^m tr(Y^m)/2, Y=X^2; odd m negates trace).
// theta^2_max = largest root of q via f32 Newton (monotone from mu0=e1).
// Taylor(exp) even/odd parts reduced mod q in two f64 cascades. Xs = X/2^r,
// theta<=8, then r matrix squarings; 2^-rk folded into the 8 scalar coeffs.
// P = E + W with W = X*O skew (O commutes with X) -> only 28 W entries.
// NOTE: fp32 peak (157 TF) is scalar v_fma_f32 -- no packed-f32 on gfx950
// (R11: float2 rewrite scalarized and regressed). No waves/EU launch bound
// (R9: forcing 3 waves/SIMD spilled).
constexpr int LG   = 512;
constexpr int NPOS = 1025;
constexpr int NMAT = NPOS * LG;
constexpr int GEN_ELEMS = 2 * LG * 64;   // 256 KB

__host__ __device__ constexpr int UI(int i, int j) { return i*7 - (i*(i-1))/2 + (j - i - 1); }
__host__ __device__ constexpr int SI(int i, int j) { return i*8 - (i*(i-1))/2 + (j - i); }

#define YSsym(a,b)  Ys [ (a)<=(b) ? SI(a,b) : SI(b,a) ]
#define Y2sym(a,b)  Y2s[ (a)<=(b) ? SI(a,b) : SI(b,a) ]
#define EEsym(a,b)  Zs [ (a)<=(b) ? SI(a,b) : SI(b,a) ]   // E lives in Zs
#define OOsym(a,b)  Y2s[ (a)<=(b) ? SI(a,b) : SI(b,a) ]   // O lives in Y2s
#define XV(i,k) ( (i)<(k) ? U[UI(i,k)] : -U[UI(k,i)] )

__device__ __forceinline__ void sq64(float (&D)[64], const float (&S)[64]) {
    #pragma unroll
    for (int i = 0; i < 8; ++i)
        #pragma unroll
        for (int j = 0; j < 8; ++j) {
            float acc = S[i*8+0] * S[0*8+j];
            #pragma unroll
            for (int k = 1; k < 8; ++k)
                acc = fmaf(S[i*8+k], S[k*8+j], acc);
            D[i*8+j] = acc;
        }
}

// transpose gen [2][512][64] -> genT [64][512][2]
__global__ __launch_bounds__(256)
void liere_tr_kernel(const float* __restrict__ g, float* __restrict__ gT) {
    int t = blockIdx.x * 256 + threadIdx.x;
    if (t >= GEN_ELEMS) return;
    int d  = t >> 15;
    int lg = (t >> 6) & 511;
    int e  = t & 63;
    gT[(size_t)e * 1024 + lg * 2 + d] = g[t];
}

template<bool TR>
__global__ __launch_bounds__(256)
void liere_expm_kernel(const float* __restrict__ pos,
                       const float* __restrict__ gen,
                       const float* __restrict__ genT,
                       float* __restrict__ out)
{
    const int bid = blockIdx.x, tid = threadIdx.x;
    const int n   = bid >> 1;                    // token, block-uniform
    const int lg  = ((bid & 1) << 8) | tid;

    float P[64];

    if (n == 0) {   // cls -> identity
        #pragma unroll
        for (int i = 0; i < 8; ++i)
            #pragma unroll
            for (int j = 0; j < 8; ++j)
                P[i*8+j] = (i == j) ? 1.f : 0.f;
    } else {
        const float p0 = pos[(n-1)*2 + 0];
        const float p1 = pos[(n-1)*2 + 1];

        // ---- strict-upper of X = p0*B0 + p1*B1 (-0.5 shift cancels) ----
        float U[28];
        if (TR) {
            #pragma unroll
            for (int i = 0; i < 8; ++i)
                #pragma unroll
                for (int j = i+1; j < 8; ++j) {
                    const int e = i*8 + j;
                    float2 v = *reinterpret_cast<const float2*>(
                                   genT + (size_t)e * 1024 + lg * 2);
                    U[UI(i,j)] = fmaf(p0, v.x, p1 * v.y);
                }
        } else {
            const float* g0 = gen + (size_t)lg * 64;
            const float* g1 = g0 + (size_t)LG * 64;
            #pragma unroll
            for (int i = 0; i < 8; ++i)
                #pragma unroll
                for (int j = i+1; j < 8; ++j) {
                    const int e = i*8 + j;
                    U[UI(i,j)] = fmaf(p0, g0[e], p1 * g1[e]);
                }
        }

        // ---- Y = X^2 (sym, 36 entries; X diag is 0), UNscaled ----
        float Ys[36];
        #pragma unroll
        for (int i = 0; i < 8; ++i)
            #pragma unroll
            for (int j = i; j < 8; ++j) {
                float acc = 0.f;
                #pragma unroll
                for (int k = 0; k < 8; ++k) {
                    if (k == i || k == j) continue;
                    acc = fmaf(XV(i,k), XV(k,j), acc);
                }
                Ys[SI(i,j)] = acc;
            }

        // ---- Y2 = Y^2 (sym), UNscaled ----
        float Y2s[36];
        #pragma unroll
        for (int i = 0; i < 8; ++i)
            #pragma unroll
            for (int j = i; j < 8; ++j) {
                float acc = YSsym(i,0) * YSsym(0,j);
                #pragma unroll
                for (int k = 1; k < 8; ++k)
                    acc = fmaf(YSsym(i,k), YSsym(k,j), acc);
                Y2s[SI(i,j)] = acc;
            }

        // ---- traces (unscaled): tr(Y), tr(Y^2), tr(Y^3), tr(Y^4) ----
        float trY = 0.f;
        #pragma unroll
        for (int i = 0; i < 8; ++i) trY += Ys[SI(i,i)];
        float dYY=0.f, oYY=0.f, dY3=0.f, oY3=0.f, d44=0.f, o44=0.f;
        #pragma unroll
        for (int i = 0; i < 8; ++i)
            #pragma unroll
            for (int j = i; j < 8; ++j) {
                float y = Ys[SI(i,j)], y2 = Y2s[SI(i,j)];
                if (i == j) { dYY=fmaf(y,y,dYY); dY3=fmaf(y,y2,dY3); d44=fmaf(y2,y2,d44); }
                else        { oYY=fmaf(y,y,oYY); oY3=fmaf(y,y2,oY3); o44=fmaf(y2,y2,o44); }
            }
        const float sYY = fmaf(2.f, oYY, dYY);   // tr(Y^2)
        const float sY3 = fmaf(2.f, oY3, dY3);   // tr(Y^3)  (negative)
        const float s44 = fmaf(2.f, o44, d44);   // tr(Y^4)

        // ---- UNscaled Newton identities: p_m = (-1)^m tr(Y^m)/2 ----
        const double P1u = -0.5 * (double)trY;
        const double P2u =  0.5 * (double)sYY;
        const double P3u = -0.5 * (double)sY3;   // odd m: negate trace
        const double P4u =  0.5 * (double)s44;
        const double E1u = P1u;
        const double E2u = 0.5 * (E1u*P1u - P2u);
        const double E3u = (1.0/3.0) * (E2u*P1u - E1u*P2u + P3u);
        const double E4u = 0.25 * (E3u*P1u - E2u*P2u + E1u*P3u - P4u);

        // ---- theta^2_max = largest root of mu^4-e1mu^3+e2mu^2-e3mu+e4 ----
        // Newton from mu0 = e1 >= root: monotone decreasing (all roots real>=0).
        const float e1f = (float)E1u, e2f = (float)E2u,
                    e3f = (float)E3u, e4f = (float)E4u;
        float mu = fmaxf(e1f, 1e-12f);
        #pragma unroll
        for (int it = 0; it < 5; ++it) {
            float f  = fmaf(fmaf(fmaf(mu - e1f, mu, e2f), mu, -e3f), mu, e4f);
            float fp = fmaf(fmaf(fmaf(4.f, mu, -3.f*e1f), mu, 2.f*e2f), mu, -e3f);
            mu = mu - __fdividef(f, fp);
        }
        mu = fmaxf(mu, 1e-12f);
        #pragma unroll
        for (int off = 32; off >= 1; off >>= 1)
            mu = fmaxf(mu, __shfl_xor(mu, off, 64));
        int r = (int)ceilf(0.5f * __log2f(mu) - 3.0f);   // theta/2^r <= 8
        if (r < 0) r = 0;
        if (r > 5) r = 5;

        // ---- scale e's: ek -> ek * 2^(-2rk) ----
        const double R2 = (double)__uint_as_float((uint32_t)(127 - 2*r) << 23);
        const double R4 = R2 * R2;
        const double E1 = E1u * R2;
        const double E2 = E2u * R4;
        const double E3 = E3u * R4 * R2;
        const double E4 = E4u * R4 * R4;

        float cf[8];
        {   // even cascade: cos-part coeffs 1/(2m)!, reduced mod quartic in mu
            double c[16] = {
                1.0, 0.5, 0.041666666666666664, 0.001388888888888889,
                2.48015873015873e-5, 2.755731922398589e-7, 2.08767569878681e-9,
                1.1470745597729725e-11, 4.779477332387385e-14,
                1.5619206968586225e-16, 4.110317623312165e-19,
                8.896791392450574e-22, 1.6117375710961184e-24,
                2.4795962632247976e-27, 3.279889237069838e-30,
                3.7699876288159054e-33
            };
            #pragma unroll
            for (int m = 15; m >= 4; --m) {
                double t = c[m];
                c[m-1] = fma(-E1, t, c[m-1]);
                c[m-2] = fma(-E2, t, c[m-2]);
                c[m-3] = fma(-E3, t, c[m-3]);
                c[m-4] = fma(-E4, t, c[m-4]);
            }
            cf[0] = (float)c[0];
            cf[2] = (float)(c[1] * R2);
            cf[4] = (float)(c[2] * R4);
            cf[6] = (float)(c[3] * R4 * R2);
        }
        {   // odd cascade: sinc-part coeffs 1/(2m+1)!
            double c[15] = {
                1.0, 0.16666666666666666, 0.008333333333333333,
                1.984126984126984e-4, 2.7557319223985893e-6,
                2.505210838544172e-8, 1.6059043836821613e-10,
                7.647163731819816e-13, 2.8114572543455206e-15,
                8.22063524662433e-18, 1.9572941063391263e-20,
                3.868170170630684e-23, 6.446950284384474e-26,
                9.183689863795546e-29, 1.1309962886447716e-31
            };
            #pragma unroll
            for (int m = 14; m >= 4; --m) {
                double t = c[m];
                c[m-1] = fma(-E1, t, c[m-1]);
                c[m-2] = fma(-E2, t, c[m-2]);
                c[m-3] = fma(-E3, t, c[m-3]);
                c[m-4] = fma(-E4, t, c[m-4]);
            }
            const double W1 = (double)__uint_as_float((uint32_t)(127 - r) << 23);
            cf[1] = (float)(c[0] * W1);
            cf[3] = (float)(c[1] * W1 * R2);
            cf[5] = (float)(c[2] * W1 * R4);
            cf[7] = (float)(c[3] * W1 * R4 * R2);
        }

        // ---- Z = Y^3 = Y * Y2 (sym) ----
        float Zs[36];
        #pragma unroll
        for (int i = 0; i < 8; ++i)
            #pragma unroll
            for (int j = i; j < 8; ++j) {
                float acc = YSsym(i,0) * Y2sym(0,j);
                #pragma unroll
                for (int k = 1; k < 8; ++k)
                    acc = fmaf(YSsym(i,k), Y2sym(k,j), acc);
                Zs[SI(i,j)] = acc;
            }

        // ---- E -> Zs, O -> Y2s (elementwise; diag const folded in fma) ----
        #pragma unroll
        for (int i = 0; i < 8; ++i)
            #pragma unroll
            for (int j = i; j < 8; ++j) {
                const int k = SI(i,j);
                float y = Ys[k], y2 = Y2s[k], z = Zs[k];
                float eb = (i == j) ? fmaf(cf[2], y, cf[0]) : cf[2] * y;
                float ob = (i == j) ? fmaf(cf[3], y, cf[1]) : cf[3] * y;
                Zs[k]  = fmaf(cf[6], z, fmaf(cf[4], y2, eb));
                Y2s[k] = fmaf(cf[7], z, fmaf(cf[5], y2, ob));
            }

        // ---- P = E + W, W = X*O skew (O commutes with X): 28 entries ----
        #pragma unroll
        for (int i = 0; i < 8; ++i) {
            P[i*8+i] = EEsym(i,i);
            #pragma unroll
            for (int j = i+1; j < 8; ++j) {
                float acc = 0.f;
                #pragma unroll
                for (int k = 0; k < 8; ++k) {
                    if (k == i) continue;
                    acc = fmaf(XV(i,k), OOsym(k,j), acc);
                }
                float e = EEsym(i,j);
                P[i*8+j] = e + acc;
                P[j*8+i] = e - acc;
            }
        }

        // ---- r squarings, ping-pong (r wave-uniform -> scalar loop) ----
        {
            float Q[64];
            int pairs = r >> 1;
            while (pairs--) { sq64(Q, P); sq64(P, Q); }
            if (r & 1) {
                sq64(Q, P);
                #pragma unroll
                for (int t = 0; t < 64; ++t) P[t] = Q[t];
            }
        }
    }

    // ---- LDS-staged coalesced stores: 2 rounds of 32 floats/thread ----
    __shared__ float4 ls[256 * 8];   // 32 KB
    float4* o4base = reinterpret_cast<float4*>(out) + (size_t)bid * 4096;
    #pragma unroll
    for (int rr = 0; rr < 2; ++rr) {
        if (rr) __syncthreads();
        #pragma unroll
        for (int j = 0; j < 8; ++j) {
            const int jj = rr*8 + j;
            ls[tid*8 + ((j + tid) & 7)] =
                make_float4(P[4*jj+0], P[4*jj+1], P[4*jj+2], P[4*jj+3]);
        }
        __syncthreads();
        #pragma unroll
        for (int k = 0; k < 8; ++k) {
            const int u = k*256 + tid;
            const int o = u >> 3, cidx = u & 7;
            o4base[o*16 + cidx + 8*rr] = ls[o*8 + ((cidx + o) & 7)];
        }
    }
}

extern "C" void kernel_launch(void* const* d_in, const int* in_sizes, int n_in,
                              void* d_out, int out_size, void* d_ws, size_t ws_size,
                              hipStream_t stream) {
    const float* pos = (const float*)d_in[0];
    const float* gen = (const float*)d_in[1];
    float* out = (float*)d_out;

    const int block = 256;
    const int grid  = NMAT / block;             // 2050

    if (ws_size >= (size_t)GEN_ELEMS * sizeof(float)) {
        float* genT = (float*)d_ws;
        liere_tr_kernel<<<GEN_ELEMS / 256, 256, 0, stream>>>(gen, genT);
        liere_expm_kernel<true><<<grid, block, 0, stream>>>(pos, gen, genT, out);
    } else {
        liere_expm_kernel<false><<<grid, block, 0, stream>>>(pos, gen, nullptr, out);
    }
}